// Round 1
// baseline (13765.634 us; speedup 1.0000x reference)
//
#include <hip/hip_runtime.h>

#define S_LEN  1024
#define H_DIM  4096
#define NHEAD  32
#define HEAD_D 128
#define RANK   16

typedef __bf16 bf16x8 __attribute__((ext_vector_type(8)));
typedef float  f32x4  __attribute__((ext_vector_type(4)));
typedef unsigned short ushort8v __attribute__((ext_vector_type(8)));

__device__ const float NF4_TAB[16] = {
    -1.0f, -0.6961928009986877f, -0.5250730514526367f, -0.39491748809814453f,
    -0.28444138169288635f, -0.18477343022823334f, -0.09105003625154495f, 0.0f,
    0.07958029955625534f, 0.16093020141124725f, 0.24611230194568634f,
    0.33791524171829224f, 0.4407098591327667f, 0.5626170039176941f,
    0.7229568362236023f, 1.0f};

__device__ __forceinline__ unsigned short f2bf(float f) {
    unsigned int u = __builtin_bit_cast(unsigned int, f);
    u = (u + 0x7FFFu + ((u >> 16) & 1u)) >> 16;   // RNE
    return (unsigned short)u;
}

// ---------------- dequant NF4 -> bf16 ----------------
__global__ __launch_bounds__(256) void dequant_nf4_kernel(
    const int* __restrict__ codes, const float* __restrict__ absmax,
    unsigned short* __restrict__ out, long n) {
    long i = ((long)blockIdx.x * 256 + threadIdx.x) * 8;
    if (i >= n) return;
    int4 c0 = *(const int4*)(codes + i);
    int4 c1 = *(const int4*)(codes + i + 4);
    float am = absmax[i >> 6];           // 8 consecutive elems share a 64-block
    ushort8v r;
    r[0] = f2bf(NF4_TAB[c0.x] * am);
    r[1] = f2bf(NF4_TAB[c0.y] * am);
    r[2] = f2bf(NF4_TAB[c0.z] * am);
    r[3] = f2bf(NF4_TAB[c0.w] * am);
    r[4] = f2bf(NF4_TAB[c1.x] * am);
    r[5] = f2bf(NF4_TAB[c1.y] * am);
    r[6] = f2bf(NF4_TAB[c1.z] * am);
    r[7] = f2bf(NF4_TAB[c1.w] * am);
    *(ushort8v*)(out + i) = r;
}

// ---------------- f32 -> bf16 ----------------
__global__ __launch_bounds__(256) void f32_to_bf16_kernel(
    const float* __restrict__ in, unsigned short* __restrict__ out, long n) {
    long i = ((long)blockIdx.x * 256 + threadIdx.x) * 8;
    if (i >= n) return;
    float4 a = *(const float4*)(in + i);
    float4 b = *(const float4*)(in + i + 4);
    ushort8v r;
    r[0] = f2bf(a.x); r[1] = f2bf(a.y); r[2] = f2bf(a.z); r[3] = f2bf(a.w);
    r[4] = f2bf(b.x); r[5] = f2bf(b.y); r[6] = f2bf(b.z); r[7] = f2bf(b.w);
    *(ushort8v*)(out + i) = r;
}

// ---------------- transpose v (f32 [S][H]) -> vT (bf16 [H][S]) ----------------
__global__ void transpose_bf16_kernel(const float* __restrict__ v,
                                      unsigned short* __restrict__ vt) {
    __shared__ float tile[32][33];
    int c0 = blockIdx.x * 32, s0 = blockIdx.y * 32;
    int tx = threadIdx.x, ty = threadIdx.y;
    tile[ty][tx] = v[(long)(s0 + ty) * H_DIM + c0 + tx];
    __syncthreads();
    vt[(long)(c0 + ty) * S_LEN + s0 + tx] = f2bf(tile[tx][ty]);
}

// ---------------- bf16 NT GEMM: C[m][n] = alpha * sum_k A[m][k]*B[n][k] ----------------
// 128x128 tile, 256 threads (4 waves, 2x2), BK=32, mfma 16x16x32 bf16.
__global__ __launch_bounds__(256) void gemm_nt(
    const unsigned short* __restrict__ A, const unsigned short* __restrict__ B,
    float* __restrict__ C, int K, int lda, int ldb, int ldc,
    long strideA, long strideB, long strideC, float alpha) {
    const unsigned short* Ab = A + (long)blockIdx.z * strideA;
    const unsigned short* Bb = B + (long)blockIdx.z * strideB;
    float* Cb = C + (long)blockIdx.z * strideC;
    const int bm = blockIdx.y * 128, bn = blockIdx.x * 128;
    __shared__ unsigned short As[128][40];   // +8 pad: 80B row stride, 16B aligned
    __shared__ unsigned short Bs[128][40];
    const int tid = threadIdx.x;
    const int lane = tid & 63, wid = tid >> 6;
    const int wm = (wid >> 1) * 64, wn = (wid & 1) * 64;
    const int srow = tid >> 2;          // 0..63
    const int scol = (tid & 3) * 8;     // 0,8,16,24
    f32x4 acc[4][4] = {};
    const int kq = (lane >> 4) * 8;     // quad*8
    const int rr = lane & 15;
    for (int k0 = 0; k0 < K; k0 += 32) {
        const unsigned short* ga = Ab + (long)(bm + srow) * lda + k0 + scol;
        const unsigned short* gb = Bb + (long)(bn + srow) * ldb + k0 + scol;
        *(uint4*)&As[srow][scol]      = *(const uint4*)ga;
        *(uint4*)&As[srow + 64][scol] = *(const uint4*)(ga + (long)64 * lda);
        *(uint4*)&Bs[srow][scol]      = *(const uint4*)gb;
        *(uint4*)&Bs[srow + 64][scol] = *(const uint4*)(gb + (long)64 * ldb);
        __syncthreads();
        bf16x8 af[4], bfr[4];
        for (int i = 0; i < 4; ++i) {
            uint4 ta = *(const uint4*)&As[wm + i * 16 + rr][kq];
            uint4 tb = *(const uint4*)&Bs[wn + i * 16 + rr][kq];
            af[i]  = __builtin_bit_cast(bf16x8, ta);
            bfr[i] = __builtin_bit_cast(bf16x8, tb);
        }
        for (int i = 0; i < 4; ++i)
            for (int j = 0; j < 4; ++j)
                acc[i][j] = __builtin_amdgcn_mfma_f32_16x16x32_bf16(
                    af[i], bfr[j], acc[i][j], 0, 0, 0);
        __syncthreads();
    }
    const int cr = (lane >> 4) * 4;     // quad*4
    const int cc = lane & 15;
    for (int i = 0; i < 4; ++i)
        for (int j = 0; j < 4; ++j) {
            float* cp = Cb + (long)(bm + wm + i * 16 + cr) * ldc + (bn + wn + j * 16 + cc);
            for (int r = 0; r < 4; ++r)
                cp[(long)r * ldc] = acc[i][j][r] * alpha;
        }
}

// ---------------- lora_a: out[m][r] = sum_k x[m][k] * la[k][r]  (fp32 exact) ----------------
__global__ __launch_bounds__(256) void lora_a_kernel(
    const float* __restrict__ x, const float* __restrict__ la,
    float* __restrict__ out) {
    int m = blockIdx.x;
    const float* xr = x + (long)m * H_DIM;
    int tid = threadIdx.x, lane = tid & 63, wid = tid >> 6;
    float s[4] = {0.f, 0.f, 0.f, 0.f};
    for (int k = lane; k < H_DIM; k += 64) {
        float xv = xr[k];
        const float* lr = la + (long)k * RANK + wid * 4;
        s[0] += xv * lr[0]; s[1] += xv * lr[1];
        s[2] += xv * lr[2]; s[3] += xv * lr[3];
    }
    for (int off = 32; off; off >>= 1)
        for (int r = 0; r < 4; ++r) s[r] += __shfl_down(s[r], off);
    if (lane == 0)
        for (int r = 0; r < 4; ++r) out[m * RANK + wid * 4 + r] = s[r];
}

// ---------------- out[m][n] += bias[n] + sum_r laout[m][r]*lb[r][n] ----------------
__global__ __launch_bounds__(256) void bias_lora_kernel(
    float* __restrict__ out, const float* __restrict__ bias,
    const float* __restrict__ laout, const float* __restrict__ lb) {
    long idx = ((long)blockIdx.x * 256 + threadIdx.x) * 4;
    long m = idx >> 12;                  // N = 4096
    int n = (int)(idx & 4095);
    float4 o = *(float4*)(out + idx);
    float4 b = *(const float4*)(bias + n);
    float lx = 0.f, ly = 0.f, lz = 0.f, lw = 0.f;
    const float* lar = laout + m * RANK;
    for (int r = 0; r < RANK; ++r) {
        float a = lar[r];
        float4 lbv = *(const float4*)(lb + (long)r * H_DIM + n);
        lx += a * lbv.x; ly += a * lbv.y; lz += a * lbv.z; lw += a * lbv.w;
    }
    o.x += b.x + lx; o.y += b.y + ly; o.z += b.z + lz; o.w += b.w + lw;
    *(float4*)(out + idx) = o;
}

// ---------------- causal softmax row, writes bf16 P in-place ----------------
__global__ __launch_bounds__(256) void softmax_causal(float* __restrict__ scores) {
    long rowbase = (long)blockIdx.x * S_LEN;
    int i = blockIdx.x & (S_LEN - 1);
    int tid = threadIdx.x, lane = tid & 63, wid = tid >> 6;
    float* row = scores + rowbase;
    int L = i + 1;
    float v[4];
    float mx = -1e30f;
    for (int t = 0; t < 4; ++t) {
        int j = tid + (t << 8);
        v[t] = (j < L) ? row[j] : -1e30f;
        mx = fmaxf(mx, v[t]);
    }
    for (int off = 32; off; off >>= 1) mx = fmaxf(mx, __shfl_xor(mx, off));
    __shared__ float red[4], red2[4];
    if (lane == 0) red[wid] = mx;
    __syncthreads();
    mx = fmaxf(fmaxf(red[0], red[1]), fmaxf(red[2], red[3]));
    float e[4], sum = 0.f;
    for (int t = 0; t < 4; ++t) {
        int j = tid + (t << 8);
        e[t] = (j < L) ? __expf(v[t] - mx) : 0.f;
        sum += e[t];
    }
    for (int off = 32; off; off >>= 1) sum += __shfl_xor(sum, off);
    if (lane == 0) red2[wid] = sum;
    __syncthreads();
    sum = red2[0] + red2[1] + red2[2] + red2[3];
    float inv = 1.f / sum;
    unsigned short* prow = (unsigned short*)scores + rowbase * 2;  // in-place, 2048-elem stride
    for (int t = 0; t < 4; ++t) {
        int j = tid + (t << 8);
        prow[j] = f2bf(e[t] * inv);
    }
}

// ---------------- histogram kernels for exact k-th selection ----------------
__global__ void hist_hi_abs(const float* __restrict__ src, long n, unsigned int* hist) {
    long i = (long)blockIdx.x * blockDim.x + threadIdx.x;
    long stride = (long)gridDim.x * blockDim.x;
    for (; i < n; i += stride) {
        unsigned int u = __builtin_bit_cast(unsigned int, src[i]) & 0x7FFFFFFFu;
        atomicAdd(&hist[u >> 16], 1u);
    }
}

__global__ void hist_lo_abs(const float* __restrict__ src, long n,
                            const unsigned int* __restrict__ sel, unsigned int* hist) {
    unsigned int target = sel[0];
    long i = (long)blockIdx.x * blockDim.x + threadIdx.x;
    long stride = (long)gridDim.x * blockDim.x;
    for (; i < n; i += stride) {
        unsigned int u = __builtin_bit_cast(unsigned int, src[i]) & 0x7FFFFFFFu;
        if ((u >> 16) == target) atomicAdd(&hist[u & 0xFFFFu], 1u);
    }
}

__global__ void hist_bf16_p(const unsigned short* __restrict__ p, long n, unsigned int* hist) {
    long i = (long)blockIdx.x * blockDim.x + threadIdx.x;
    long stride = (long)gridDim.x * blockDim.x;
    unsigned int zc = 0;
    for (; i < n; i += stride) {
        long r = i >> 10; int c = (int)(i & 1023);
        unsigned short b = p[(r << 11) + c];     // row stride 2048
        if (b == 0) zc++;
        else atomicAdd(&hist[b], 1u);
    }
    if (zc) atomicAdd(&hist[0], zc);
}

// mode 0: find hi bin, sel[0]=bin, sel[1]=rank within bin
// mode 1: final low bin; bits=(sel[0]<<16)|bin -> *outp
// mode 2: bf16 single pass; bits=bin<<16 -> *outp
__global__ __launch_bounds__(256) void scan_hist(
    const unsigned int* __restrict__ hist, unsigned int* sel, float* outp,
    long k, int mode) {
    __shared__ unsigned int part[256];
    int t = threadIdx.x;
    unsigned int s = 0;
    for (int b = 0; b < 256; ++b) s += hist[(t << 8) | b];
    part[t] = s;
    __syncthreads();
    if (t == 0) {
        long kk = (mode == 1) ? (long)sel[1] : k;
        long c = 0;
        int ch = 0;
        for (; ch < 256; ++ch) {
            if (c + (long)part[ch] >= kk) break;
            c += part[ch];
        }
        int bin = ch << 8;
        for (;; ++bin) {
            unsigned int h = hist[bin];
            if (c + (long)h >= kk) break;
            c += h;
        }
        if (mode == 0) { sel[0] = (unsigned int)bin; sel[1] = (unsigned int)(kk - c); }
        else {
            unsigned int bits = (mode == 1) ? ((sel[0] << 16) | (unsigned int)bin)
                                            : ((unsigned int)bin << 16);
            *outp = __builtin_bit_cast(float, bits);
        }
    }
}

// ==================================================================
extern "C" void kernel_launch(void* const* d_in, const int* in_sizes, int n_in,
                              void* d_out, int out_size, void* d_ws, size_t ws_size,
                              hipStream_t stream) {
    (void)in_sizes; (void)n_in; (void)out_size; (void)ws_size;
    const float* x = (const float*)d_in[0];
    const int*   wcodes[4] = {(const int*)d_in[1], (const int*)d_in[6],
                              (const int*)d_in[11], (const int*)d_in[16]};
    const float* wabs[4]   = {(const float*)d_in[2], (const float*)d_in[7],
                              (const float*)d_in[12], (const float*)d_in[17]};
    const float* bias[4]   = {(const float*)d_in[3], (const float*)d_in[8],
                              (const float*)d_in[13], (const float*)d_in[18]};
    const float* lA[4]     = {(const float*)d_in[4], (const float*)d_in[9],
                              (const float*)d_in[14], (const float*)d_in[19]};
    const float* lB[4]     = {(const float*)d_in[5], (const float*)d_in[10],
                              (const float*)d_in[15], (const float*)d_in[20]};

    char* wp = (char*)d_ws;
    auto alloc = [&](size_t bytes) {
        char* p = wp; wp += (bytes + 255) & ~(size_t)255; return p;
    };
    const size_t SH  = (size_t)S_LEN * H_DIM;       // 4,194,304
    unsigned short* xb = (unsigned short*)alloc(SH * 2);
    unsigned short* qb = (unsigned short*)alloc(SH * 2);
    unsigned short* kb = (unsigned short*)alloc(SH * 2);
    unsigned short* vT = (unsigned short*)alloc(SH * 2);
    unsigned short* ob = (unsigned short*)alloc(SH * 2);
    unsigned short* Wd = (unsigned short*)alloc((size_t)H_DIM * H_DIM * 2);
    float* qf = (float*)alloc(SH * 4);
    float* kf = (float*)alloc(SH * 4);
    float* vf = (float*)alloc(SH * 4);
    float* of = (float*)alloc(SH * 4);
    float* laout = (float*)alloc((size_t)S_LEN * RANK * 4);
    unsigned int* histA = (unsigned int*)alloc(65536 * 4);
    unsigned int* histB = (unsigned int*)alloc(65536 * 4);
    unsigned int* sel   = (unsigned int*)alloc(256);
    float* scores = (float*)alloc((size_t)NHEAD * S_LEN * S_LEN * 4);   // also holds P (bf16, in-place)

    float* out_final = (float*)d_out;
    float* out_kth   = out_final + SH;

    auto gemm = [&](const unsigned short* A, const unsigned short* B, float* C,
                    int M, int N, int K, int lda, int ldb, int ldc,
                    long sA, long sB, long sC, int batch, float alpha) {
        dim3 g(N / 128, M / 128, batch);
        gemm_nt<<<g, 256, 0, stream>>>(A, B, C, K, lda, ldb, ldc, sA, sB, sC, alpha);
    };
    auto select_f32 = [&](const float* src, long n, int slot) {
        hipMemsetAsync(histA, 0, 65536 * 4, stream);
        hist_hi_abs<<<2048, 256, 0, stream>>>(src, n, histA);
        scan_hist<<<1, 256, 0, stream>>>(histA, sel, nullptr, n / 2, 0);
        hipMemsetAsync(histB, 0, 65536 * 4, stream);
        hist_lo_abs<<<2048, 256, 0, stream>>>(src, n, sel, histB);
        scan_hist<<<1, 256, 0, stream>>>(histB, sel, out_kth + slot, 0, 1);
    };

    const long nW = (long)H_DIM * H_DIM;
    // x -> bf16
    f32_to_bf16_kernel<<<2048, 256, 0, stream>>>(x, xb, (long)SH);

    // Q/K/V projections
    float* outs[3] = {qf, kf, vf};
    for (int p = 0; p < 3; ++p) {
        dequant_nf4_kernel<<<8192, 256, 0, stream>>>(wcodes[p], wabs[p], Wd, nW);
        gemm(xb, Wd, outs[p], S_LEN, H_DIM, H_DIM, H_DIM, H_DIM, H_DIM, 0, 0, 0, 1, 1.0f);
        lora_a_kernel<<<S_LEN, 256, 0, stream>>>(x, lA[p], laout);
        bias_lora_kernel<<<4096, 256, 0, stream>>>(outs[p], bias[p], laout, lB[p]);
    }

    // attention inputs
    f32_to_bf16_kernel<<<2048, 256, 0, stream>>>(qf, qb, (long)SH);
    f32_to_bf16_kernel<<<2048, 256, 0, stream>>>(kf, kb, (long)SH);
    transpose_bf16_kernel<<<dim3(H_DIM / 32, S_LEN / 32), dim3(32, 32), 0, stream>>>(vf, vT);

    // scores = q.kT / sqrt(128)   [32][1024][1024]
    gemm(qb, kb, scores, S_LEN, S_LEN, HEAD_D, H_DIM, H_DIM, S_LEN,
         128, 128, (long)S_LEN * S_LEN, NHEAD, 0.08838834764831845f);
    softmax_causal<<<NHEAD * S_LEN, 256, 0, stream>>>(scores);
    // o = P.v   (P bf16 in scores buffer, row stride 2048)
    gemm((const unsigned short*)scores, vT, of, S_LEN, HEAD_D, S_LEN,
         2 * S_LEN, S_LEN, H_DIM,
         (long)S_LEN * 2 * S_LEN, (long)HEAD_D * S_LEN, 128, NHEAD, 1.0f);

    // O projection -> d_out
    f32_to_bf16_kernel<<<2048, 256, 0, stream>>>(of, ob, (long)SH);
    dequant_nf4_kernel<<<8192, 256, 0, stream>>>(wcodes[3], wabs[3], Wd, nW);
    gemm(ob, Wd, out_final, S_LEN, H_DIM, H_DIM, H_DIM, H_DIM, H_DIM, 0, 0, 0, 1, 1.0f);
    lora_a_kernel<<<S_LEN, 256, 0, stream>>>(of, lA[3], laout);
    bias_lora_kernel<<<4096, 256, 0, stream>>>(out_final, bias[3], laout, lB[3]);

    // k-th smallest values: x, qh, kh, vh, a, o  (slots 0..5)
    select_f32(x,  (long)SH, 0);
    select_f32(qf, (long)SH, 1);
    select_f32(kf, (long)SH, 2);
    select_f32(vf, (long)SH, 3);
    select_f32(of, (long)SH, 5);
    hipMemsetAsync(histA, 0, 65536 * 4, stream);
    hist_bf16_p<<<8192, 256, 0, stream>>>((const unsigned short*)scores,
                                          (long)NHEAD * S_LEN * S_LEN, histA);
    scan_hist<<<1, 256, 0, stream>>>(histA, sel, out_kth + 4,
                                     (long)NHEAD * S_LEN * S_LEN / 2, 2);
}

// Round 2
// 1484.174 us; speedup vs baseline: 9.2749x; 9.2749x over previous
//
#include <hip/hip_runtime.h>

#define S_LEN  1024
#define H_DIM  4096
#define NHEAD  32
#define HEAD_D 128
#define RANK   16

typedef __bf16 bf16x8 __attribute__((ext_vector_type(8)));
typedef float  f32x4  __attribute__((ext_vector_type(4)));
typedef unsigned short ushort8v __attribute__((ext_vector_type(8)));

__device__ const float NF4_TAB[16] = {
    -1.0f, -0.6961928009986877f, -0.5250730514526367f, -0.39491748809814453f,
    -0.28444138169288635f, -0.18477343022823334f, -0.09105003625154495f, 0.0f,
    0.07958029955625534f, 0.16093020141124725f, 0.24611230194568634f,
    0.33791524171829224f, 0.4407098591327667f, 0.5626170039176941f,
    0.7229568362236023f, 1.0f};

__device__ __forceinline__ unsigned short f2bf(float f) {
    unsigned int u = __builtin_bit_cast(unsigned int, f);
    u = (u + 0x7FFFu + ((u >> 16) & 1u)) >> 16;   // RNE
    return (unsigned short)u;
}

// ---------------- dequant NF4 -> bf16 ----------------
__global__ __launch_bounds__(256) void dequant_nf4_kernel(
    const int* __restrict__ codes, const float* __restrict__ absmax,
    unsigned short* __restrict__ out, long n) {
    long i = ((long)blockIdx.x * 256 + threadIdx.x) * 8;
    if (i >= n) return;
    int4 c0 = *(const int4*)(codes + i);
    int4 c1 = *(const int4*)(codes + i + 4);
    float am = absmax[i >> 6];           // 8 consecutive elems share a 64-block
    ushort8v r;
    r[0] = f2bf(NF4_TAB[c0.x] * am);
    r[1] = f2bf(NF4_TAB[c0.y] * am);
    r[2] = f2bf(NF4_TAB[c0.z] * am);
    r[3] = f2bf(NF4_TAB[c0.w] * am);
    r[4] = f2bf(NF4_TAB[c1.x] * am);
    r[5] = f2bf(NF4_TAB[c1.y] * am);
    r[6] = f2bf(NF4_TAB[c1.z] * am);
    r[7] = f2bf(NF4_TAB[c1.w] * am);
    *(ushort8v*)(out + i) = r;
}

// ---------------- f32 -> bf16 ----------------
__global__ __launch_bounds__(256) void f32_to_bf16_kernel(
    const float* __restrict__ in, unsigned short* __restrict__ out, long n) {
    long i = ((long)blockIdx.x * 256 + threadIdx.x) * 8;
    if (i >= n) return;
    float4 a = *(const float4*)(in + i);
    float4 b = *(const float4*)(in + i + 4);
    ushort8v r;
    r[0] = f2bf(a.x); r[1] = f2bf(a.y); r[2] = f2bf(a.z); r[3] = f2bf(a.w);
    r[4] = f2bf(b.x); r[5] = f2bf(b.y); r[6] = f2bf(b.z); r[7] = f2bf(b.w);
    *(ushort8v*)(out + i) = r;
}

// ---------------- transpose v (f32 [S][H]) -> vT (bf16 [H][S]) ----------------
__global__ void transpose_bf16_kernel(const float* __restrict__ v,
                                      unsigned short* __restrict__ vt) {
    __shared__ float tile[32][33];
    int c0 = blockIdx.x * 32, s0 = blockIdx.y * 32;
    int tx = threadIdx.x, ty = threadIdx.y;
    tile[ty][tx] = v[(long)(s0 + ty) * H_DIM + c0 + tx];
    __syncthreads();
    vt[(long)(c0 + ty) * S_LEN + s0 + tx] = f2bf(tile[tx][ty]);
}

// ---------------- bf16 NT GEMM: C[m][n] = alpha * sum_k A[m][k]*B[n][k] ----------------
// 128x128 tile, 256 threads (4 waves, 2x2), BK=32, mfma 16x16x32 bf16.
__global__ __launch_bounds__(256) void gemm_nt(
    const unsigned short* __restrict__ A, const unsigned short* __restrict__ B,
    float* __restrict__ C, int K, int lda, int ldb, int ldc,
    long strideA, long strideB, long strideC, float alpha) {
    const unsigned short* Ab = A + (long)blockIdx.z * strideA;
    const unsigned short* Bb = B + (long)blockIdx.z * strideB;
    float* Cb = C + (long)blockIdx.z * strideC;
    const int bm = blockIdx.y * 128, bn = blockIdx.x * 128;
    __shared__ unsigned short As[128][40];   // +8 pad: 80B row stride, 16B aligned
    __shared__ unsigned short Bs[128][40];
    const int tid = threadIdx.x;
    const int lane = tid & 63, wid = tid >> 6;
    const int wm = (wid >> 1) * 64, wn = (wid & 1) * 64;
    const int srow = tid >> 2;          // 0..63
    const int scol = (tid & 3) * 8;     // 0,8,16,24
    f32x4 acc[4][4] = {};
    const int kq = (lane >> 4) * 8;     // quad*8
    const int rr = lane & 15;
    for (int k0 = 0; k0 < K; k0 += 32) {
        const unsigned short* ga = Ab + (long)(bm + srow) * lda + k0 + scol;
        const unsigned short* gb = Bb + (long)(bn + srow) * ldb + k0 + scol;
        *(uint4*)&As[srow][scol]      = *(const uint4*)ga;
        *(uint4*)&As[srow + 64][scol] = *(const uint4*)(ga + (long)64 * lda);
        *(uint4*)&Bs[srow][scol]      = *(const uint4*)gb;
        *(uint4*)&Bs[srow + 64][scol] = *(const uint4*)(gb + (long)64 * ldb);
        __syncthreads();
        bf16x8 af[4], bfr[4];
        for (int i = 0; i < 4; ++i) {
            uint4 ta = *(const uint4*)&As[wm + i * 16 + rr][kq];
            uint4 tb = *(const uint4*)&Bs[wn + i * 16 + rr][kq];
            af[i]  = __builtin_bit_cast(bf16x8, ta);
            bfr[i] = __builtin_bit_cast(bf16x8, tb);
        }
        for (int i = 0; i < 4; ++i)
            for (int j = 0; j < 4; ++j)
                acc[i][j] = __builtin_amdgcn_mfma_f32_16x16x32_bf16(
                    af[i], bfr[j], acc[i][j], 0, 0, 0);
        __syncthreads();
    }
    const int cr = (lane >> 4) * 4;     // quad*4
    const int cc = lane & 15;
    for (int i = 0; i < 4; ++i)
        for (int j = 0; j < 4; ++j) {
            float* cp = Cb + (long)(bm + wm + i * 16 + cr) * ldc + (bn + wn + j * 16 + cc);
            for (int r = 0; r < 4; ++r)
                cp[(long)r * ldc] = acc[i][j][r] * alpha;
        }
}

// ---------------- lora_a: out[m][r] = sum_k x[m][k] * la[k][r]  (fp32 exact) ----------------
__global__ __launch_bounds__(256) void lora_a_kernel(
    const float* __restrict__ x, const float* __restrict__ la,
    float* __restrict__ out) {
    int m = blockIdx.x;
    const float* xr = x + (long)m * H_DIM;
    int tid = threadIdx.x, lane = tid & 63, wid = tid >> 6;
    float s[4] = {0.f, 0.f, 0.f, 0.f};
    for (int k = lane; k < H_DIM; k += 64) {
        float xv = xr[k];
        const float* lr = la + (long)k * RANK + wid * 4;
        s[0] += xv * lr[0]; s[1] += xv * lr[1];
        s[2] += xv * lr[2]; s[3] += xv * lr[3];
    }
    for (int off = 32; off; off >>= 1)
        for (int r = 0; r < 4; ++r) s[r] += __shfl_down(s[r], off);
    if (lane == 0)
        for (int r = 0; r < 4; ++r) out[m * RANK + wid * 4 + r] = s[r];
}

// ---------------- out[m][n] += bias[n] + sum_r laout[m][r]*lb[r][n] ----------------
__global__ __launch_bounds__(256) void bias_lora_kernel(
    float* __restrict__ out, const float* __restrict__ bias,
    const float* __restrict__ laout, const float* __restrict__ lb) {
    long idx = ((long)blockIdx.x * 256 + threadIdx.x) * 4;
    long m = idx >> 12;                  // N = 4096
    int n = (int)(idx & 4095);
    float4 o = *(float4*)(out + idx);
    float4 b = *(const float4*)(bias + n);
    float lx = 0.f, ly = 0.f, lz = 0.f, lw = 0.f;
    const float* lar = laout + m * RANK;
    for (int r = 0; r < RANK; ++r) {
        float a = lar[r];
        float4 lbv = *(const float4*)(lb + (long)r * H_DIM + n);
        lx += a * lbv.x; ly += a * lbv.y; lz += a * lbv.z; lw += a * lbv.w;
    }
    o.x += b.x + lx; o.y += b.y + ly; o.z += b.z + lz; o.w += b.w + lw;
    *(float4*)(out + idx) = o;
}

// ---------------- causal softmax row, writes bf16 P in-place ----------------
__global__ __launch_bounds__(256) void softmax_causal(float* __restrict__ scores) {
    long rowbase = (long)blockIdx.x * S_LEN;
    int i = blockIdx.x & (S_LEN - 1);
    int tid = threadIdx.x, lane = tid & 63, wid = tid >> 6;
    float* row = scores + rowbase;
    int L = i + 1;
    float v[4];
    float mx = -1e30f;
    for (int t = 0; t < 4; ++t) {
        int j = tid + (t << 8);
        v[t] = (j < L) ? row[j] : -1e30f;
        mx = fmaxf(mx, v[t]);
    }
    for (int off = 32; off; off >>= 1) mx = fmaxf(mx, __shfl_xor(mx, off));
    __shared__ float red[4], red2[4];
    if (lane == 0) red[wid] = mx;
    __syncthreads();
    mx = fmaxf(fmaxf(red[0], red[1]), fmaxf(red[2], red[3]));
    float e[4], sum = 0.f;
    for (int t = 0; t < 4; ++t) {
        int j = tid + (t << 8);
        e[t] = (j < L) ? __expf(v[t] - mx) : 0.f;
        sum += e[t];
    }
    for (int off = 32; off; off >>= 1) sum += __shfl_xor(sum, off);
    if (lane == 0) red2[wid] = sum;
    __syncthreads();
    sum = red2[0] + red2[1] + red2[2] + red2[3];
    float inv = 1.f / sum;
    unsigned short* prow = (unsigned short*)scores + rowbase * 2;  // in-place, 2048-elem stride
    for (int t = 0; t < 4; ++t) {
        int j = tid + (t << 8);
        prow[j] = f2bf(e[t] * inv);
    }
}

// ---------------- histogram kernels for exact k-th selection ----------------
// LDS-privatized: abs-fp32 hi-16 bits <= 0x7F80 -> 32768 bins (128 KB LDS).
__global__ __launch_bounds__(256, 1) void hist_hi_abs(
    const float* __restrict__ src, long n4, unsigned int* __restrict__ hist) {
    __shared__ unsigned int lh[32768];
    int t = threadIdx.x;
    for (int b = t; b < 32768; b += 256) lh[b] = 0u;
    __syncthreads();
    long i = (long)blockIdx.x * 256 + t;
    long stride = (long)gridDim.x * 256;
    for (; i < n4; i += stride) {
        float4 v = *(const float4*)(src + i * 4);
        unsigned int u0 = (__builtin_bit_cast(unsigned int, v.x) & 0x7FFFFFFFu) >> 16;
        unsigned int u1 = (__builtin_bit_cast(unsigned int, v.y) & 0x7FFFFFFFu) >> 16;
        unsigned int u2 = (__builtin_bit_cast(unsigned int, v.z) & 0x7FFFFFFFu) >> 16;
        unsigned int u3 = (__builtin_bit_cast(unsigned int, v.w) & 0x7FFFFFFFu) >> 16;
        atomicAdd(&lh[u0], 1u);
        atomicAdd(&lh[u1], 1u);
        atomicAdd(&lh[u2], 1u);
        atomicAdd(&lh[u3], 1u);
    }
    __syncthreads();
    for (int b = t; b < 32768; b += 256) {
        unsigned int c = lh[b];
        if (c) atomicAdd(&hist[b], c);
    }
}

__global__ __launch_bounds__(256) void hist_lo_abs(
    const float* __restrict__ src, long n4,
    const unsigned int* __restrict__ sel, unsigned int* __restrict__ hist) {
    unsigned int target = sel[0];
    long i = (long)blockIdx.x * 256 + threadIdx.x;
    long stride = (long)gridDim.x * 256;
    for (; i < n4; i += stride) {
        float4 v = *(const float4*)(src + i * 4);
        unsigned int u0 = __builtin_bit_cast(unsigned int, v.x) & 0x7FFFFFFFu;
        unsigned int u1 = __builtin_bit_cast(unsigned int, v.y) & 0x7FFFFFFFu;
        unsigned int u2 = __builtin_bit_cast(unsigned int, v.z) & 0x7FFFFFFFu;
        unsigned int u3 = __builtin_bit_cast(unsigned int, v.w) & 0x7FFFFFFFu;
        if ((u0 >> 16) == target) atomicAdd(&hist[u0 & 0xFFFFu], 1u);
        if ((u1 >> 16) == target) atomicAdd(&hist[u1 & 0xFFFFu], 1u);
        if ((u2 >> 16) == target) atomicAdd(&hist[u2 & 0xFFFFu], 1u);
        if ((u3 >> 16) == target) atomicAdd(&hist[u3 & 0xFFFFu], 1u);
    }
}

// P (softmax probs) in [0,1] -> bf16 bits <= 0x3F80 -> 16384 bins (64 KB LDS).
// P stored with row stride 2048 shorts, 1024 valid per row. nv = #ushort8 vectors.
__global__ __launch_bounds__(256, 2) void hist_bf16_p(
    const unsigned short* __restrict__ p, long nv, unsigned int* __restrict__ hist) {
    __shared__ unsigned int lh[16384];
    int t = threadIdx.x;
    for (int b = t; b < 16384; b += 256) lh[b] = 0u;
    __syncthreads();
    long i = (long)blockIdx.x * 256 + t;
    long stride = (long)gridDim.x * 256;
    unsigned int zc = 0;
    for (; i < nv; i += stride) {
        long r = i >> 7;                    // 128 vectors per 1024-col row
        int c = (int)(i & 127) * 8;
        ushort8v v = *(const ushort8v*)(p + (r << 11) + c);
        for (int j = 0; j < 8; ++j) {
            unsigned int b = v[j];
            if (b == 0) zc++;
            else atomicAdd(&lh[b < 16384u ? b : 16383u], 1u);
        }
    }
    if (zc) atomicAdd(&lh[0], zc);
    __syncthreads();
    for (int b = t; b < 16384; b += 256) {
        unsigned int c = lh[b];
        if (c) atomicAdd(&hist[b], c);
    }
}

// mode 0: find hi bin, sel[0]=bin, sel[1]=rank within bin
// mode 1: final low bin; bits=(sel[0]<<16)|bin -> *outp
// mode 2: bf16 single pass; bits=bin<<16 -> *outp
__global__ __launch_bounds__(256) void scan_hist(
    const unsigned int* __restrict__ hist, unsigned int* sel, float* outp,
    long k, int mode) {
    __shared__ unsigned int part[256];
    int t = threadIdx.x;
    unsigned int s = 0;
    for (int b = 0; b < 256; ++b) s += hist[(t << 8) | b];
    part[t] = s;
    __syncthreads();
    if (t == 0) {
        long kk = (mode == 1) ? (long)sel[1] : k;
        long c = 0;
        int ch = 0;
        for (; ch < 256; ++ch) {
            if (c + (long)part[ch] >= kk) break;
            c += part[ch];
        }
        int bin = ch << 8;
        for (;; ++bin) {
            unsigned int h = hist[bin];
            if (c + (long)h >= kk) break;
            c += h;
        }
        if (mode == 0) { sel[0] = (unsigned int)bin; sel[1] = (unsigned int)(kk - c); }
        else {
            unsigned int bits = (mode == 1) ? ((sel[0] << 16) | (unsigned int)bin)
                                            : ((unsigned int)bin << 16);
            *outp = __builtin_bit_cast(float, bits);
        }
    }
}

// ==================================================================
extern "C" void kernel_launch(void* const* d_in, const int* in_sizes, int n_in,
                              void* d_out, int out_size, void* d_ws, size_t ws_size,
                              hipStream_t stream) {
    (void)in_sizes; (void)n_in; (void)out_size; (void)ws_size;
    const float* x = (const float*)d_in[0];
    const int*   wcodes[4] = {(const int*)d_in[1], (const int*)d_in[6],
                              (const int*)d_in[11], (const int*)d_in[16]};
    const float* wabs[4]   = {(const float*)d_in[2], (const float*)d_in[7],
                              (const float*)d_in[12], (const float*)d_in[17]};
    const float* bias[4]   = {(const float*)d_in[3], (const float*)d_in[8],
                              (const float*)d_in[13], (const float*)d_in[18]};
    const float* lA[4]     = {(const float*)d_in[4], (const float*)d_in[9],
                              (const float*)d_in[14], (const float*)d_in[19]};
    const float* lB[4]     = {(const float*)d_in[5], (const float*)d_in[10],
                              (const float*)d_in[15], (const float*)d_in[20]};

    char* wp = (char*)d_ws;
    auto alloc = [&](size_t bytes) {
        char* p = wp; wp += (bytes + 255) & ~(size_t)255; return p;
    };
    const size_t SH  = (size_t)S_LEN * H_DIM;       // 4,194,304
    unsigned short* xb = (unsigned short*)alloc(SH * 2);
    unsigned short* qb = (unsigned short*)alloc(SH * 2);
    unsigned short* kb = (unsigned short*)alloc(SH * 2);
    unsigned short* vT = (unsigned short*)alloc(SH * 2);
    unsigned short* ob = (unsigned short*)alloc(SH * 2);
    unsigned short* Wd = (unsigned short*)alloc((size_t)H_DIM * H_DIM * 2);
    float* qf = (float*)alloc(SH * 4);
    float* kf = (float*)alloc(SH * 4);
    float* vf = (float*)alloc(SH * 4);
    float* of = (float*)alloc(SH * 4);
    float* laout = (float*)alloc((size_t)S_LEN * RANK * 4);
    unsigned int* histA = (unsigned int*)alloc(65536 * 4);
    unsigned int* histB = (unsigned int*)alloc(65536 * 4);
    unsigned int* sel   = (unsigned int*)alloc(256);
    float* scores = (float*)alloc((size_t)NHEAD * S_LEN * S_LEN * 4);   // also holds P (bf16, in-place)

    float* out_final = (float*)d_out;
    float* out_kth   = out_final + SH;

    auto gemm = [&](const unsigned short* A, const unsigned short* B, float* C,
                    int M, int N, int K, int lda, int ldb, int ldc,
                    long sA, long sB, long sC, int batch, float alpha) {
        dim3 g(N / 128, M / 128, batch);
        gemm_nt<<<g, 256, 0, stream>>>(A, B, C, K, lda, ldb, ldc, sA, sB, sC, alpha);
    };
    auto select_f32 = [&](const float* src, long n, int slot) {
        hipMemsetAsync(histA, 0, 65536 * 4, stream);
        hist_hi_abs<<<512, 256, 0, stream>>>(src, n / 4, histA);
        scan_hist<<<1, 256, 0, stream>>>(histA, sel, nullptr, n / 2, 0);
        hipMemsetAsync(histB, 0, 65536 * 4, stream);
        hist_lo_abs<<<1024, 256, 0, stream>>>(src, n / 4, sel, histB);
        scan_hist<<<1, 256, 0, stream>>>(histB, sel, out_kth + slot, 0, 1);
    };

    const long nW = (long)H_DIM * H_DIM;
    // x -> bf16
    f32_to_bf16_kernel<<<2048, 256, 0, stream>>>(x, xb, (long)SH);

    // Q/K/V projections
    float* outs[3] = {qf, kf, vf};
    for (int p = 0; p < 3; ++p) {
        dequant_nf4_kernel<<<8192, 256, 0, stream>>>(wcodes[p], wabs[p], Wd, nW);
        gemm(xb, Wd, outs[p], S_LEN, H_DIM, H_DIM, H_DIM, H_DIM, H_DIM, 0, 0, 0, 1, 1.0f);
        lora_a_kernel<<<S_LEN, 256, 0, stream>>>(x, lA[p], laout);
        bias_lora_kernel<<<4096, 256, 0, stream>>>(outs[p], bias[p], laout, lB[p]);
    }

    // attention inputs
    f32_to_bf16_kernel<<<2048, 256, 0, stream>>>(qf, qb, (long)SH);
    f32_to_bf16_kernel<<<2048, 256, 0, stream>>>(kf, kb, (long)SH);
    transpose_bf16_kernel<<<dim3(H_DIM / 32, S_LEN / 32), dim3(32, 32), 0, stream>>>(vf, vT);

    // scores = q.kT / sqrt(128)   [32][1024][1024]
    gemm(qb, kb, scores, S_LEN, S_LEN, HEAD_D, H_DIM, H_DIM, S_LEN,
         128, 128, (long)S_LEN * S_LEN, NHEAD, 0.08838834764831845f);
    softmax_causal<<<NHEAD * S_LEN, 256, 0, stream>>>(scores);
    // o = P.v   (P bf16 in scores buffer, row stride 2048)
    gemm((const unsigned short*)scores, vT, of, S_LEN, HEAD_D, S_LEN,
         2 * S_LEN, S_LEN, H_DIM,
         (long)S_LEN * 2 * S_LEN, (long)HEAD_D * S_LEN, 128, NHEAD, 1.0f);

    // O projection -> d_out
    f32_to_bf16_kernel<<<2048, 256, 0, stream>>>(of, ob, (long)SH);
    dequant_nf4_kernel<<<8192, 256, 0, stream>>>(wcodes[3], wabs[3], Wd, nW);
    gemm(ob, Wd, out_final, S_LEN, H_DIM, H_DIM, H_DIM, H_DIM, H_DIM, 0, 0, 0, 1, 1.0f);
    lora_a_kernel<<<S_LEN, 256, 0, stream>>>(of, lA[3], laout);
    bias_lora_kernel<<<4096, 256, 0, stream>>>(out_final, bias[3], laout, lB[3]);

    // k-th smallest values: x, qh, kh, vh, a, o  (slots 0..5)
    select_f32(x,  (long)SH, 0);
    select_f32(qf, (long)SH, 1);
    select_f32(kf, (long)SH, 2);
    select_f32(vf, (long)SH, 3);
    select_f32(of, (long)SH, 5);
    hipMemsetAsync(histA, 0, 65536 * 4, stream);
    hist_bf16_p<<<1024, 256, 0, stream>>>((const unsigned short*)scores,
                                          (long)NHEAD * S_LEN * S_LEN / 8, histA);
    scan_hist<<<1, 256, 0, stream>>>(histA, sel, out_kth + 4,
                                     (long)NHEAD * S_LEN * S_LEN / 2, 2);
}

// Round 3
// 1321.226 us; speedup vs baseline: 10.4188x; 1.1233x over previous
//
#include <hip/hip_runtime.h>

#define S_LEN  1024
#define H_DIM  4096
#define NHEAD  32
#define HEAD_D 128
#define RANK   16

typedef __bf16 bf16x8 __attribute__((ext_vector_type(8)));
typedef float  f32x4  __attribute__((ext_vector_type(4)));
typedef unsigned short ushort8v __attribute__((ext_vector_type(8)));

#define GLOAD_LDS16(g, l) __builtin_amdgcn_global_load_lds( \
    (const __attribute__((address_space(1))) unsigned int*)(g), \
    (__attribute__((address_space(3))) unsigned int*)(l), 16, 0, 0)

__device__ const float NF4_TAB[16] = {
    -1.0f, -0.6961928009986877f, -0.5250730514526367f, -0.39491748809814453f,
    -0.28444138169288635f, -0.18477343022823334f, -0.09105003625154495f, 0.0f,
    0.07958029955625534f, 0.16093020141124725f, 0.24611230194568634f,
    0.33791524171829224f, 0.4407098591327667f, 0.5626170039176941f,
    0.7229568362236023f, 1.0f};

__device__ __forceinline__ unsigned short f2bf(float f) {
    unsigned int u = __builtin_bit_cast(unsigned int, f);
    u = (u + 0x7FFFu + ((u >> 16) & 1u)) >> 16;   // RNE
    return (unsigned short)u;
}

// ---------------- dequant NF4 -> bf16 ----------------
__global__ __launch_bounds__(256) void dequant_nf4_kernel(
    const int* __restrict__ codes, const float* __restrict__ absmax,
    unsigned short* __restrict__ out, long n) {
    long i = ((long)blockIdx.x * 256 + threadIdx.x) * 8;
    if (i >= n) return;
    int4 c0 = *(const int4*)(codes + i);
    int4 c1 = *(const int4*)(codes + i + 4);
    float am = absmax[i >> 6];           // 8 consecutive elems share a 64-block
    ushort8v r;
    r[0] = f2bf(NF4_TAB[c0.x] * am);
    r[1] = f2bf(NF4_TAB[c0.y] * am);
    r[2] = f2bf(NF4_TAB[c0.z] * am);
    r[3] = f2bf(NF4_TAB[c0.w] * am);
    r[4] = f2bf(NF4_TAB[c1.x] * am);
    r[5] = f2bf(NF4_TAB[c1.y] * am);
    r[6] = f2bf(NF4_TAB[c1.z] * am);
    r[7] = f2bf(NF4_TAB[c1.w] * am);
    *(ushort8v*)(out + i) = r;
}

// ---------------- f32 -> bf16 ----------------
__global__ __launch_bounds__(256) void f32_to_bf16_kernel(
    const float* __restrict__ in, unsigned short* __restrict__ out, long n) {
    long i = ((long)blockIdx.x * 256 + threadIdx.x) * 8;
    if (i >= n) return;
    float4 a = *(const float4*)(in + i);
    float4 b = *(const float4*)(in + i + 4);
    ushort8v r;
    r[0] = f2bf(a.x); r[1] = f2bf(a.y); r[2] = f2bf(a.z); r[3] = f2bf(a.w);
    r[4] = f2bf(b.x); r[5] = f2bf(b.y); r[6] = f2bf(b.z); r[7] = f2bf(b.w);
    *(ushort8v*)(out + i) = r;
}

// ---------------- transpose v (f32 [S][H]) -> vT (bf16 [H][S]) ----------------
__global__ void transpose_bf16_kernel(const float* __restrict__ v,
                                      unsigned short* __restrict__ vt) {
    __shared__ float tile[32][33];
    int c0 = blockIdx.x * 32, s0 = blockIdx.y * 32;
    int tx = threadIdx.x, ty = threadIdx.y;
    tile[ty][tx] = v[(long)(s0 + ty) * H_DIM + c0 + tx];
    __syncthreads();
    vt[(long)(c0 + ty) * S_LEN + s0 + tx] = f2bf(tile[tx][ty]);
}

// ---------------- bf16 NT GEMM: C[m][n] = alpha * sum_k A[m][k]*B[n][k] ----------------
// m97 recipe: 128x128 tile, BK=32, unpadded LDS [128][32], global_load_lds width=16.
__global__ __launch_bounds__(256) void gemm_nt(
    const unsigned short* __restrict__ A, const unsigned short* __restrict__ B,
    float* __restrict__ C, int K, int lda, int ldb, int ldc,
    long strideA, long strideB, long strideC, float alpha) {
    const unsigned short* Ab = A + (long)blockIdx.z * strideA;
    const unsigned short* Bb = B + (long)blockIdx.z * strideB;
    float* Cb = C + (long)blockIdx.z * strideC;
    const int bm = blockIdx.y * 128, bn = blockIdx.x * 128;
    __shared__ unsigned short As[128][32];   // UNPADDED: global_load_lds lane-order
    __shared__ unsigned short Bs[128][32];
    const int tid = threadIdx.x;
    const int lane = tid & 63, wid = tid >> 6;
    const int wm = (wid >> 1) * 64, wn = (wid & 1) * 64;
    // staging: wave w covers 16 rows/round; lane -> row wid*16 + lane/4, col (lane&3)*8
    const int sr = wid * 16 + (lane >> 2);
    const int sc = (lane & 3) * 8;
    const unsigned short* gA0 = Ab + (long)(bm + sr) * lda + sc;
    const unsigned short* gA1 = gA0 + (long)64 * lda;
    const unsigned short* gB0 = Bb + (long)(bn + sr) * ldb + sc;
    const unsigned short* gB1 = gB0 + (long)64 * ldb;
    unsigned short* lA0 = &As[wid * 16][0];
    unsigned short* lA1 = &As[64 + wid * 16][0];
    unsigned short* lB0 = &Bs[wid * 16][0];
    unsigned short* lB1 = &Bs[64 + wid * 16][0];
    f32x4 acc[4][4] = {};
    const int kq = (lane >> 4) * 8;     // quad*8
    const int rr = lane & 15;
    for (int k0 = 0; k0 < K; k0 += 32) {
        GLOAD_LDS16(gA0 + k0, lA0);
        GLOAD_LDS16(gA1 + k0, lA1);
        GLOAD_LDS16(gB0 + k0, lB0);
        GLOAD_LDS16(gB1 + k0, lB1);
        __syncthreads();                 // vmcnt(0) drain + barrier
        bf16x8 af[4], bfr[4];
        for (int i = 0; i < 4; ++i) {
            uint4 ta = *(const uint4*)&As[wm + i * 16 + rr][kq];
            uint4 tb = *(const uint4*)&Bs[wn + i * 16 + rr][kq];
            af[i]  = __builtin_bit_cast(bf16x8, ta);
            bfr[i] = __builtin_bit_cast(bf16x8, tb);
        }
        for (int i = 0; i < 4; ++i)
            for (int j = 0; j < 4; ++j)
                acc[i][j] = __builtin_amdgcn_mfma_f32_16x16x32_bf16(
                    af[i], bfr[j], acc[i][j], 0, 0, 0);
        __syncthreads();
    }
    const int cr = (lane >> 4) * 4;     // quad*4
    const int cc = lane & 15;
    for (int i = 0; i < 4; ++i)
        for (int j = 0; j < 4; ++j) {
            float* cp = Cb + (long)(bm + wm + i * 16 + cr) * ldc + (bn + wn + j * 16 + cc);
            for (int r = 0; r < 4; ++r)
                cp[(long)r * ldc] = acc[i][j][r] * alpha;
        }
}

// ---------------- lora_a: out[m][r] = sum_k x[m][k] * la[k][r]  (fp32 exact) ----------------
__global__ __launch_bounds__(256) void lora_a_kernel(
    const float* __restrict__ x, const float* __restrict__ la,
    float* __restrict__ out) {
    int m = blockIdx.x;
    const float* xr = x + (long)m * H_DIM;
    int tid = threadIdx.x, lane = tid & 63, wid = tid >> 6;
    float s[4] = {0.f, 0.f, 0.f, 0.f};
    for (int k = lane; k < H_DIM; k += 64) {
        float xv = xr[k];
        const float* lr = la + (long)k * RANK + wid * 4;
        s[0] += xv * lr[0]; s[1] += xv * lr[1];
        s[2] += xv * lr[2]; s[3] += xv * lr[3];
    }
    for (int off = 32; off; off >>= 1)
        for (int r = 0; r < 4; ++r) s[r] += __shfl_down(s[r], off);
    if (lane == 0)
        for (int r = 0; r < 4; ++r) out[m * RANK + wid * 4 + r] = s[r];
}

// ---------------- out[m][n] += bias[n] + sum_r laout[m][r]*lb[r][n] ----------------
__global__ __launch_bounds__(256) void bias_lora_kernel(
    float* __restrict__ out, const float* __restrict__ bias,
    const float* __restrict__ laout, const float* __restrict__ lb) {
    long idx = ((long)blockIdx.x * 256 + threadIdx.x) * 4;
    long m = idx >> 12;                  // N = 4096
    int n = (int)(idx & 4095);
    float4 o = *(float4*)(out + idx);
    float4 b = *(const float4*)(bias + n);
    float lx = 0.f, ly = 0.f, lz = 0.f, lw = 0.f;
    const float* lar = laout + m * RANK;
    for (int r = 0; r < RANK; ++r) {
        float a = lar[r];
        float4 lbv = *(const float4*)(lb + (long)r * H_DIM + n);
        lx += a * lbv.x; ly += a * lbv.y; lz += a * lbv.z; lw += a * lbv.w;
    }
    o.x += b.x + lx; o.y += b.y + ly; o.z += b.z + lz; o.w += b.w + lw;
    *(float4*)(out + idx) = o;
}

// ---------------- causal softmax row, writes bf16 P in-place ----------------
__global__ __launch_bounds__(256) void softmax_causal(float* __restrict__ scores) {
    long rowbase = (long)blockIdx.x * S_LEN;
    int i = blockIdx.x & (S_LEN - 1);
    int tid = threadIdx.x, lane = tid & 63, wid = tid >> 6;
    float* row = scores + rowbase;
    int L = i + 1;
    float v[4];
    float mx = -1e30f;
    for (int t = 0; t < 4; ++t) {
        int j = tid + (t << 8);
        v[t] = (j < L) ? row[j] : -1e30f;
        mx = fmaxf(mx, v[t]);
    }
    for (int off = 32; off; off >>= 1) mx = fmaxf(mx, __shfl_xor(mx, off));
    __shared__ float red[4], red2[4];
    if (lane == 0) red[wid] = mx;
    __syncthreads();
    mx = fmaxf(fmaxf(red[0], red[1]), fmaxf(red[2], red[3]));
    float e[4], sum = 0.f;
    for (int t = 0; t < 4; ++t) {
        int j = tid + (t << 8);
        e[t] = (j < L) ? __expf(v[t] - mx) : 0.f;
        sum += e[t];
    }
    for (int off = 32; off; off >>= 1) sum += __shfl_xor(sum, off);
    if (lane == 0) red2[wid] = sum;
    __syncthreads();
    sum = red2[0] + red2[1] + red2[2] + red2[3];
    float inv = 1.f / sum;
    unsigned short* prow = (unsigned short*)scores + rowbase * 2;  // in-place, 2048-elem stride
    for (int t = 0; t < 4; ++t) {
        int j = tid + (t << 8);
        prow[j] = f2bf(e[t] * inv);
    }
}

// ---------------- histogram kernels for exact k-th selection ----------------
// LDS-privatized: abs-fp32 hi-16 bits <= 0x7F80 -> 32768 bins (128 KB LDS).
__global__ __launch_bounds__(256, 1) void hist_hi_abs(
    const float* __restrict__ src, long n4, unsigned int* __restrict__ hist) {
    __shared__ unsigned int lh[32768];
    int t = threadIdx.x;
    for (int b = t; b < 32768; b += 256) lh[b] = 0u;
    __syncthreads();
    long i = (long)blockIdx.x * 256 + t;
    long stride = (long)gridDim.x * 256;
    for (; i < n4; i += stride) {
        float4 v = *(const float4*)(src + i * 4);
        unsigned int u0 = (__builtin_bit_cast(unsigned int, v.x) & 0x7FFFFFFFu) >> 16;
        unsigned int u1 = (__builtin_bit_cast(unsigned int, v.y) & 0x7FFFFFFFu) >> 16;
        unsigned int u2 = (__builtin_bit_cast(unsigned int, v.z) & 0x7FFFFFFFu) >> 16;
        unsigned int u3 = (__builtin_bit_cast(unsigned int, v.w) & 0x7FFFFFFFu) >> 16;
        atomicAdd(&lh[u0], 1u);
        atomicAdd(&lh[u1], 1u);
        atomicAdd(&lh[u2], 1u);
        atomicAdd(&lh[u3], 1u);
    }
    __syncthreads();
    for (int b = t; b < 32768; b += 256) {
        unsigned int c = lh[b];
        if (c) atomicAdd(&hist[b], c);
    }
}

__global__ __launch_bounds__(256) void hist_lo_abs(
    const float* __restrict__ src, long n4,
    const unsigned int* __restrict__ sel, unsigned int* __restrict__ hist) {
    unsigned int target = sel[0];
    long i = (long)blockIdx.x * 256 + threadIdx.x;
    long stride = (long)gridDim.x * 256;
    for (; i < n4; i += stride) {
        float4 v = *(const float4*)(src + i * 4);
        unsigned int u0 = __builtin_bit_cast(unsigned int, v.x) & 0x7FFFFFFFu;
        unsigned int u1 = __builtin_bit_cast(unsigned int, v.y) & 0x7FFFFFFFu;
        unsigned int u2 = __builtin_bit_cast(unsigned int, v.z) & 0x7FFFFFFFu;
        unsigned int u3 = __builtin_bit_cast(unsigned int, v.w) & 0x7FFFFFFFu;
        if ((u0 >> 16) == target) atomicAdd(&hist[u0 & 0xFFFFu], 1u);
        if ((u1 >> 16) == target) atomicAdd(&hist[u1 & 0xFFFFu], 1u);
        if ((u2 >> 16) == target) atomicAdd(&hist[u2 & 0xFFFFu], 1u);
        if ((u3 >> 16) == target) atomicAdd(&hist[u3 & 0xFFFFu], 1u);
    }
}

// P (softmax probs) in [0,1] -> bf16 bits <= 0x3F80 -> 16384 bins (64 KB LDS).
__global__ __launch_bounds__(256, 2) void hist_bf16_p(
    const unsigned short* __restrict__ p, long nv, unsigned int* __restrict__ hist) {
    __shared__ unsigned int lh[16384];
    int t = threadIdx.x;
    for (int b = t; b < 16384; b += 256) lh[b] = 0u;
    __syncthreads();
    long i = (long)blockIdx.x * 256 + t;
    long stride = (long)gridDim.x * 256;
    unsigned int zc = 0;
    for (; i < nv; i += stride) {
        long r = i >> 7;                    // 128 vectors per 1024-col row
        int c = (int)(i & 127) * 8;
        ushort8v v = *(const ushort8v*)(p + (r << 11) + c);
        for (int j = 0; j < 8; ++j) {
            unsigned int b = v[j];
            if (b == 0) zc++;
            else atomicAdd(&lh[b < 16384u ? b : 16383u], 1u);
        }
    }
    if (zc) atomicAdd(&lh[0], zc);
    __syncthreads();
    for (int b = t; b < 16384; b += 256) {
        unsigned int c = lh[b];
        if (c) atomicAdd(&hist[b], c);
    }
}

// mode 0: find hi bin, sel[0]=bin, sel[1]=rank within bin
// mode 1: final low bin; bits=(sel[0]<<16)|bin -> *outp
// mode 2: bf16 single pass; bits=bin<<16 -> *outp
__global__ __launch_bounds__(256) void scan_hist(
    const unsigned int* __restrict__ hist, unsigned int* sel, float* outp,
    long k, int mode) {
    __shared__ unsigned int part[256];
    int t = threadIdx.x;
    unsigned int s = 0;
    for (int b = 0; b < 256; ++b) s += hist[(t << 8) | b];
    part[t] = s;
    __syncthreads();
    if (t == 0) {
        long kk = (mode == 1) ? (long)sel[1] : k;
        long c = 0;
        int ch = 0;
        for (; ch < 256; ++ch) {
            if (c + (long)part[ch] >= kk) break;
            c += part[ch];
        }
        int bin = ch << 8;
        for (;; ++bin) {
            unsigned int h = hist[bin];
            if (c + (long)h >= kk) break;
            c += h;
        }
        if (mode == 0) { sel[0] = (unsigned int)bin; sel[1] = (unsigned int)(kk - c); }
        else {
            unsigned int bits = (mode == 1) ? ((sel[0] << 16) | (unsigned int)bin)
                                            : ((unsigned int)bin << 16);
            *outp = __builtin_bit_cast(float, bits);
        }
    }
}

// ==================================================================
extern "C" void kernel_launch(void* const* d_in, const int* in_sizes, int n_in,
                              void* d_out, int out_size, void* d_ws, size_t ws_size,
                              hipStream_t stream) {
    (void)in_sizes; (void)n_in; (void)out_size; (void)ws_size;
    const float* x = (const float*)d_in[0];
    const int*   wcodes[4] = {(const int*)d_in[1], (const int*)d_in[6],
                              (const int*)d_in[11], (const int*)d_in[16]};
    const float* wabs[4]   = {(const float*)d_in[2], (const float*)d_in[7],
                              (const float*)d_in[12], (const float*)d_in[17]};
    const float* bias[4]   = {(const float*)d_in[3], (const float*)d_in[8],
                              (const float*)d_in[13], (const float*)d_in[18]};
    const float* lA[4]     = {(const float*)d_in[4], (const float*)d_in[9],
                              (const float*)d_in[14], (const float*)d_in[19]};
    const float* lB[4]     = {(const float*)d_in[5], (const float*)d_in[10],
                              (const float*)d_in[15], (const float*)d_in[20]};

    char* wp = (char*)d_ws;
    auto alloc = [&](size_t bytes) {
        char* p = wp; wp += (bytes + 255) & ~(size_t)255; return p;
    };
    const size_t SH  = (size_t)S_LEN * H_DIM;       // 4,194,304
    const long   nW  = (long)H_DIM * H_DIM;
    unsigned short* xb = (unsigned short*)alloc(SH * 2);
    unsigned short* qb = (unsigned short*)alloc(SH * 2);   // qb,kb contiguous
    unsigned short* kb = (unsigned short*)alloc(SH * 2);
    unsigned short* vT = (unsigned short*)alloc(SH * 2);
    unsigned short* ob = (unsigned short*)alloc(SH * 2);
    unsigned short* Wd = (unsigned short*)alloc((size_t)nW * 2);   // O-proj weight
    float* qf = (float*)alloc(SH * 4);                     // qf,kf,vf,of contiguous
    float* kf = (float*)alloc(SH * 4);
    float* vf = (float*)alloc(SH * 4);
    float* of = (float*)alloc(SH * 4);
    float* laout = (float*)alloc((size_t)S_LEN * RANK * 4);
    unsigned int* histA = (unsigned int*)alloc(65536 * 4);
    unsigned int* histB = (unsigned int*)alloc(65536 * 4);
    unsigned int* sel   = (unsigned int*)alloc(256);
    // scores (128 MB) doubles as QKV dequant buffer (96 MB) before attention
    float* scores = (float*)alloc((size_t)NHEAD * S_LEN * S_LEN * 4);
    unsigned short* Wqkv = (unsigned short*)scores;

    float* out_final = (float*)d_out;
    float* out_kth   = out_final + SH;

    auto gemm = [&](const unsigned short* A, const unsigned short* B, float* C,
                    int M, int N, int K, int lda, int ldb, int ldc,
                    long sA, long sB, long sC, int batch, float alpha) {
        dim3 g(N / 128, M / 128, batch);
        gemm_nt<<<g, 256, 0, stream>>>(A, B, C, K, lda, ldb, ldc, sA, sB, sC, alpha);
    };
    auto select_f32 = [&](const float* src, long n, int slot) {
        hipMemsetAsync(histA, 0, 65536 * 4, stream);
        hist_hi_abs<<<512, 256, 0, stream>>>(src, n / 4, histA);
        scan_hist<<<1, 256, 0, stream>>>(histA, sel, nullptr, n / 2, 0);
        hipMemsetAsync(histB, 0, 65536 * 4, stream);
        hist_lo_abs<<<1024, 256, 0, stream>>>(src, n / 4, sel, histB);
        scan_hist<<<1, 256, 0, stream>>>(histB, sel, out_kth + slot, 0, 1);
    };

    // x -> bf16
    f32_to_bf16_kernel<<<2048, 256, 0, stream>>>(x, xb, (long)SH);

    // Q/K/V projections: dequant all 3 weights, then ONE z=3 batched GEMM (768 blocks)
    for (int p = 0; p < 3; ++p)
        dequant_nf4_kernel<<<8192, 256, 0, stream>>>(wcodes[p], wabs[p],
                                                     Wqkv + (size_t)p * nW, nW);
    gemm(xb, Wqkv, qf, S_LEN, H_DIM, H_DIM, H_DIM, H_DIM, H_DIM,
         0, nW, (long)SH, 3, 1.0f);
    for (int p = 0; p < 3; ++p) {
        float* outs[3] = {qf, kf, vf};
        lora_a_kernel<<<S_LEN, 256, 0, stream>>>(x, lA[p], laout);
        bias_lora_kernel<<<4096, 256, 0, stream>>>(outs[p], bias[p], laout, lB[p]);
    }

    // attention inputs: q,k -> bf16 (one launch, contiguous), v -> vT
    f32_to_bf16_kernel<<<4096, 256, 0, stream>>>(qf, qb, (long)(2 * SH));
    transpose_bf16_kernel<<<dim3(H_DIM / 32, S_LEN / 32), dim3(32, 32), 0, stream>>>(vf, vT);

    // scores = q.kT / sqrt(128)   [32][1024][1024]
    gemm(qb, kb, scores, S_LEN, S_LEN, HEAD_D, H_DIM, H_DIM, S_LEN,
         128, 128, (long)S_LEN * S_LEN, NHEAD, 0.08838834764831845f);
    softmax_causal<<<NHEAD * S_LEN, 256, 0, stream>>>(scores);
    // o = P.v   (P bf16 in scores buffer, row stride 2048)
    gemm((const unsigned short*)scores, vT, of, S_LEN, HEAD_D, S_LEN,
         2 * S_LEN, S_LEN, H_DIM,
         (long)S_LEN * 2 * S_LEN, (long)HEAD_D * S_LEN, 128, NHEAD, 1.0f);

    // O projection -> d_out
    f32_to_bf16_kernel<<<2048, 256, 0, stream>>>(of, ob, (long)SH);
    dequant_nf4_kernel<<<8192, 256, 0, stream>>>(wcodes[3], wabs[3], Wd, nW);
    gemm(ob, Wd, out_final, S_LEN, H_DIM, H_DIM, H_DIM, H_DIM, H_DIM, 0, 0, 0, 1, 1.0f);
    lora_a_kernel<<<S_LEN, 256, 0, stream>>>(of, lA[3], laout);
    bias_lora_kernel<<<4096, 256, 0, stream>>>(out_final, bias[3], laout, lB[3]);

    // k-th smallest values: x, qh, kh, vh, a, o  (slots 0..5)
    select_f32(x,  (long)SH, 0);
    select_f32(qf, (long)SH, 1);
    select_f32(kf, (long)SH, 2);
    select_f32(vf, (long)SH, 3);
    select_f32(of, (long)SH, 5);
    hipMemsetAsync(histA, 0, 65536 * 4, stream);
    hist_bf16_p<<<1024, 256, 0, stream>>>((const unsigned short*)scores,
                                          (long)NHEAD * S_LEN * S_LEN / 8, histA);
    scan_hist<<<1, 256, 0, stream>>>(histA, sel, out_kth + 4,
                                     (long)NHEAD * S_LEN * S_LEN / 2, 2);
}

// Round 4
// 992.946 us; speedup vs baseline: 13.8634x; 1.3306x over previous
//
#include <hip/hip_runtime.h>

#define S_LEN  1024
#define H_DIM  4096
#define NHEAD  32
#define HEAD_D 128
#define RANK   16

typedef __bf16 bf16x8 __attribute__((ext_vector_type(8)));
typedef float  f32x4  __attribute__((ext_vector_type(4)));
typedef unsigned short ushort8v __attribute__((ext_vector_type(8)));

#define GLOAD_LDS16(g, l) __builtin_amdgcn_global_load_lds( \
    (const __attribute__((address_space(1))) unsigned int*)(g), \
    (__attribute__((address_space(3))) unsigned int*)(l), 16, 0, 0)

__device__ const float NF4_TAB[16] = {
    -1.0f, -0.6961928009986877f, -0.5250730514526367f, -0.39491748809814453f,
    -0.28444138169288635f, -0.18477343022823334f, -0.09105003625154495f, 0.0f,
    0.07958029955625534f, 0.16093020141124725f, 0.24611230194568634f,
    0.33791524171829224f, 0.4407098591327667f, 0.5626170039176941f,
    0.7229568362236023f, 1.0f};

__device__ __forceinline__ unsigned short f2bf(float f) {
    unsigned int u = __builtin_bit_cast(unsigned int, f);
    u = (u + 0x7FFFu + ((u >> 16) & 1u)) >> 16;   // RNE
    return (unsigned short)u;
}

// ---------------- dequant NF4 -> bf16 (3 weights in one launch) ----------------
__global__ __launch_bounds__(256) void dequant3_kernel(
    const int* __restrict__ c0, const int* __restrict__ c1, const int* __restrict__ c2,
    const float* __restrict__ a0, const float* __restrict__ a1, const float* __restrict__ a2,
    unsigned short* __restrict__ out, long n) {
    int t = blockIdx.y;
    const int* codes = (t == 0) ? c0 : (t == 1) ? c1 : c2;
    const float* absmax = (t == 0) ? a0 : (t == 1) ? a1 : a2;
    unsigned short* o = out + (size_t)t * n;
    long i = ((long)blockIdx.x * 256 + threadIdx.x) * 8;
    if (i >= n) return;
    int4 cc0 = *(const int4*)(codes + i);
    int4 cc1 = *(const int4*)(codes + i + 4);
    float am = absmax[i >> 6];
    ushort8v r;
    r[0] = f2bf(NF4_TAB[cc0.x] * am);
    r[1] = f2bf(NF4_TAB[cc0.y] * am);
    r[2] = f2bf(NF4_TAB[cc0.z] * am);
    r[3] = f2bf(NF4_TAB[cc0.w] * am);
    r[4] = f2bf(NF4_TAB[cc1.x] * am);
    r[5] = f2bf(NF4_TAB[cc1.y] * am);
    r[6] = f2bf(NF4_TAB[cc1.z] * am);
    r[7] = f2bf(NF4_TAB[cc1.w] * am);
    *(ushort8v*)(o + i) = r;
}

__global__ __launch_bounds__(256) void dequant_nf4_kernel(
    const int* __restrict__ codes, const float* __restrict__ absmax,
    unsigned short* __restrict__ out, long n) {
    long i = ((long)blockIdx.x * 256 + threadIdx.x) * 8;
    if (i >= n) return;
    int4 c0 = *(const int4*)(codes + i);
    int4 c1 = *(const int4*)(codes + i + 4);
    float am = absmax[i >> 6];
    ushort8v r;
    r[0] = f2bf(NF4_TAB[c0.x] * am);
    r[1] = f2bf(NF4_TAB[c0.y] * am);
    r[2] = f2bf(NF4_TAB[c0.z] * am);
    r[3] = f2bf(NF4_TAB[c0.w] * am);
    r[4] = f2bf(NF4_TAB[c1.x] * am);
    r[5] = f2bf(NF4_TAB[c1.y] * am);
    r[6] = f2bf(NF4_TAB[c1.z] * am);
    r[7] = f2bf(NF4_TAB[c1.w] * am);
    *(ushort8v*)(out + i) = r;
}

// ---------------- f32 -> bf16 ----------------
__global__ __launch_bounds__(256) void f32_to_bf16_kernel(
    const float* __restrict__ in, unsigned short* __restrict__ out, long n) {
    long i = ((long)blockIdx.x * 256 + threadIdx.x) * 8;
    if (i >= n) return;
    float4 a = *(const float4*)(in + i);
    float4 b = *(const float4*)(in + i + 4);
    ushort8v r;
    r[0] = f2bf(a.x); r[1] = f2bf(a.y); r[2] = f2bf(a.z); r[3] = f2bf(a.w);
    r[4] = f2bf(b.x); r[5] = f2bf(b.y); r[6] = f2bf(b.z); r[7] = f2bf(b.w);
    *(ushort8v*)(out + i) = r;
}

// ---------------- transpose v (f32 [S][H]) -> vT (bf16 [H][S]) ----------------
__global__ void transpose_bf16_kernel(const float* __restrict__ v,
                                      unsigned short* __restrict__ vt) {
    __shared__ float tile[32][33];
    int c0 = blockIdx.x * 32, s0 = blockIdx.y * 32;
    int tx = threadIdx.x, ty = threadIdx.y;
    tile[ty][tx] = v[(long)(s0 + ty) * H_DIM + c0 + tx];
    __syncthreads();
    vt[(long)(c0 + ty) * S_LEN + s0 + tx] = f2bf(tile[tx][ty]);
}

// ---------------- bf16 NT GEMM: C[m][n] = alpha * sum_k A[m][k]*B[n][k] ----------------
// m97 recipe: 128x128 tile, BK=32, unpadded LDS, global_load_lds width=16.
// mode 0: plain batched (z=batch). mode 1: causal triangular tile grid (x=tri idx, z=head).
// mode 2: batched + K limited to bm+128 (causal PV). mode 3: split-K2 (z=half, C/C2).
__global__ __launch_bounds__(256) void gemm_nt(
    const unsigned short* __restrict__ A, const unsigned short* __restrict__ B,
    float* __restrict__ C, float* __restrict__ C2, int K, int lda, int ldb, int ldc,
    long strideA, long strideB, long strideC, float alpha, int mode) {
    int bm, bn;
    int k0s = 0, k0e = K;
    const unsigned short *Ab, *Bb;
    float* Cb;
    if (mode == 1) {
        int i = blockIdx.x;
        int tm = (int)((sqrtf(8.f * i + 1.f) - 1.f) * 0.5f);
        if ((tm + 1) * (tm + 2) / 2 <= i) tm++;
        if (tm * (tm + 1) / 2 > i) tm--;
        int tn = i - tm * (tm + 1) / 2;
        bm = tm * 128; bn = tn * 128;
        Ab = A + (long)blockIdx.z * strideA;
        Bb = B + (long)blockIdx.z * strideB;
        Cb = C + (long)blockIdx.z * strideC;
    } else if (mode == 3) {
        bm = blockIdx.y * 128; bn = blockIdx.x * 128;
        Ab = A; Bb = B;
        int Kh = K >> 1;
        k0s = blockIdx.z ? Kh : 0;
        k0e = blockIdx.z ? K : Kh;
        Cb = blockIdx.z ? C2 : C;
    } else {
        bm = blockIdx.y * 128; bn = blockIdx.x * 128;
        Ab = A + (long)blockIdx.z * strideA;
        Bb = B + (long)blockIdx.z * strideB;
        Cb = C + (long)blockIdx.z * strideC;
        if (mode == 2) { int kl = bm + 128; if (kl < k0e) k0e = kl; }
    }
    __shared__ unsigned short As[128][32];   // UNPADDED: global_load_lds lane-order
    __shared__ unsigned short Bs[128][32];
    const int tid = threadIdx.x;
    const int lane = tid & 63, wid = tid >> 6;
    const int wm = (wid >> 1) * 64, wn = (wid & 1) * 64;
    const int sr = wid * 16 + (lane >> 2);
    const int sc = (lane & 3) * 8;
    const unsigned short* gA0 = Ab + (long)(bm + sr) * lda + sc;
    const unsigned short* gA1 = gA0 + (long)64 * lda;
    const unsigned short* gB0 = Bb + (long)(bn + sr) * ldb + sc;
    const unsigned short* gB1 = gB0 + (long)64 * ldb;
    unsigned short* lA0 = &As[wid * 16][0];
    unsigned short* lA1 = &As[64 + wid * 16][0];
    unsigned short* lB0 = &Bs[wid * 16][0];
    unsigned short* lB1 = &Bs[64 + wid * 16][0];
    f32x4 acc[4][4] = {};
    const int kq = (lane >> 4) * 8;
    const int rr = lane & 15;
    for (int k0 = k0s; k0 < k0e; k0 += 32) {
        GLOAD_LDS16(gA0 + k0, lA0);
        GLOAD_LDS16(gA1 + k0, lA1);
        GLOAD_LDS16(gB0 + k0, lB0);
        GLOAD_LDS16(gB1 + k0, lB1);
        __syncthreads();
        bf16x8 af[4], bfr[4];
        for (int i = 0; i < 4; ++i) {
            uint4 ta = *(const uint4*)&As[wm + i * 16 + rr][kq];
            uint4 tb = *(const uint4*)&Bs[wn + i * 16 + rr][kq];
            af[i]  = __builtin_bit_cast(bf16x8, ta);
            bfr[i] = __builtin_bit_cast(bf16x8, tb);
        }
        for (int i = 0; i < 4; ++i)
            for (int j = 0; j < 4; ++j)
                acc[i][j] = __builtin_amdgcn_mfma_f32_16x16x32_bf16(
                    af[i], bfr[j], acc[i][j], 0, 0, 0);
        __syncthreads();
    }
    const int cr = (lane >> 4) * 4;
    const int cc = lane & 15;
    for (int i = 0; i < 4; ++i)
        for (int j = 0; j < 4; ++j) {
            float* cp = Cb + (long)(bm + wm + i * 16 + cr) * ldc + (bn + wn + j * 16 + cc);
            for (int r = 0; r < 4; ++r)
                cp[(long)r * ldc] = acc[i][j][r] * alpha;
        }
}

// ---------------- lora_a: out[m][r] = sum_k x[m][k] * la[k][r] ----------------
__global__ __launch_bounds__(256) void lora_a_kernel(
    const float* __restrict__ x, const float* __restrict__ la,
    float* __restrict__ out) {
    int m = blockIdx.x;
    const float* xr = x + (long)m * H_DIM;
    int tid = threadIdx.x, lane = tid & 63, wid = tid >> 6;
    float s[4] = {0.f, 0.f, 0.f, 0.f};
    for (int k = lane; k < H_DIM; k += 64) {
        float xv = xr[k];
        const float* lr = la + (long)k * RANK + wid * 4;
        s[0] += xv * lr[0]; s[1] += xv * lr[1];
        s[2] += xv * lr[2]; s[3] += xv * lr[3];
    }
    for (int off = 32; off; off >>= 1)
        for (int r = 0; r < 4; ++r) s[r] += __shfl_down(s[r], off);
    if (lane == 0)
        for (int r = 0; r < 4; ++r) out[m * RANK + wid * 4 + r] = s[r];
}

// ---------------- out[m][n] += (part2) + bias[n] + sum_r laout[m][r]*lb[r][n] ----------------
__global__ __launch_bounds__(256) void bias_lora_kernel(
    float* __restrict__ out, const float* __restrict__ part2,
    const float* __restrict__ bias,
    const float* __restrict__ laout, const float* __restrict__ lb) {
    long idx = ((long)blockIdx.x * 256 + threadIdx.x) * 4;
    long m = idx >> 12;                  // N = 4096
    int n = (int)(idx & 4095);
    float4 o = *(float4*)(out + idx);
    if (part2) {
        float4 p = *(const float4*)(part2 + idx);
        o.x += p.x; o.y += p.y; o.z += p.z; o.w += p.w;
    }
    float4 b = *(const float4*)(bias + n);
    float lx = 0.f, ly = 0.f, lz = 0.f, lw = 0.f;
    const float* lar = laout + m * RANK;
    for (int r = 0; r < RANK; ++r) {
        float a = lar[r];
        float4 lbv = *(const float4*)(lb + (long)r * H_DIM + n);
        lx += a * lbv.x; ly += a * lbv.y; lz += a * lbv.z; lw += a * lbv.w;
    }
    o.x += b.x + lx; o.y += b.y + ly; o.z += b.z + lz; o.w += b.w + lw;
    *(float4*)(out + idx) = o;
}

// ---------------- causal softmax row, writes bf16 P in-place ----------------
__global__ __launch_bounds__(256) void softmax_causal(float* __restrict__ scores) {
    long rowbase = (long)blockIdx.x * S_LEN;
    int i = blockIdx.x & (S_LEN - 1);
    int tid = threadIdx.x, lane = tid & 63, wid = tid >> 6;
    float* row = scores + rowbase;
    int L = i + 1;
    float v[4];
    float mx = -1e30f;
    for (int t = 0; t < 4; ++t) {
        int j = tid + (t << 8);
        v[t] = (j < L) ? row[j] : -1e30f;
        mx = fmaxf(mx, v[t]);
    }
    for (int off = 32; off; off >>= 1) mx = fmaxf(mx, __shfl_xor(mx, off));
    __shared__ float red[4], red2[4];
    if (lane == 0) red[wid] = mx;
    __syncthreads();
    mx = fmaxf(fmaxf(red[0], red[1]), fmaxf(red[2], red[3]));
    float e[4], sum = 0.f;
    for (int t = 0; t < 4; ++t) {
        int j = tid + (t << 8);
        e[t] = (j < L) ? __expf(v[t] - mx) : 0.f;
        sum += e[t];
    }
    for (int off = 32; off; off >>= 1) sum += __shfl_xor(sum, off);
    if (lane == 0) red2[wid] = sum;
    __syncthreads();
    sum = red2[0] + red2[1] + red2[2] + red2[3];
    float inv = 1.f / sum;
    unsigned short* prow = (unsigned short*)scores + rowbase * 2;
    for (int t = 0; t < 4; ++t) {
        int j = tid + (t << 8);
        prow[j] = f2bf(e[t] * inv);
    }
}

// ---------------- merged 5-tensor exact k-th selection ----------------
// Pass 1: abs-fp32 hi-16, clamped to 16384 bins (64 KB LDS, 2 blocks/CU).
// Safe: all medians << 2.0 (= bin 16384); clamped mass is above selected bin.
__global__ __launch_bounds__(256, 2) void hist5_hi(
    const float* __restrict__ x, const float* __restrict__ qf,
    const float* __restrict__ kf, const float* __restrict__ vf,
    const float* __restrict__ of, long n4, unsigned int* __restrict__ hist) {
    __shared__ unsigned int lh[16384];
    int t = threadIdx.x, ten = blockIdx.y;
    const float* src = (ten == 0) ? x : (ten == 1) ? qf : (ten == 2) ? kf
                     : (ten == 3) ? vf : of;
    unsigned int* gh = hist + (long)ten * 16384;
    for (int b = t; b < 16384; b += 256) lh[b] = 0u;
    __syncthreads();
    long i = (long)blockIdx.x * 256 + t;
    long stride = (long)gridDim.x * 256;
    for (; i < n4; i += stride) {
        float4 v = *(const float4*)(src + i * 4);
        unsigned int u0 = (__builtin_bit_cast(unsigned int, v.x) & 0x7FFFFFFFu) >> 16;
        unsigned int u1 = (__builtin_bit_cast(unsigned int, v.y) & 0x7FFFFFFFu) >> 16;
        unsigned int u2 = (__builtin_bit_cast(unsigned int, v.z) & 0x7FFFFFFFu) >> 16;
        unsigned int u3 = (__builtin_bit_cast(unsigned int, v.w) & 0x7FFFFFFFu) >> 16;
        atomicAdd(&lh[u0 < 16384u ? u0 : 16383u], 1u);
        atomicAdd(&lh[u1 < 16384u ? u1 : 16383u], 1u);
        atomicAdd(&lh[u2 < 16384u ? u2 : 16383u], 1u);
        atomicAdd(&lh[u3 < 16384u ? u3 : 16383u], 1u);
    }
    __syncthreads();
    for (int b = t; b < 16384; b += 256) {
        unsigned int c = lh[b];
        if (c) atomicAdd(&gh[b], c);
    }
}

// Pass 2: low-16 bits for entries matching the selected hi bin (sparse -> global atomics).
__global__ __launch_bounds__(256) void hist5_lo(
    const float* __restrict__ x, const float* __restrict__ qf,
    const float* __restrict__ kf, const float* __restrict__ vf,
    const float* __restrict__ of, long n4,
    const unsigned int* __restrict__ sel, unsigned int* __restrict__ hist) {
    int ten = blockIdx.y;
    const float* src = (ten == 0) ? x : (ten == 1) ? qf : (ten == 2) ? kf
                     : (ten == 3) ? vf : of;
    unsigned int* gh = hist + (long)ten * 65536;
    unsigned int target = sel[2 * ten];
    long i = (long)blockIdx.x * 256 + threadIdx.x;
    long stride = (long)gridDim.x * 256;
    for (; i < n4; i += stride) {
        float4 v = *(const float4*)(src + i * 4);
        unsigned int u0 = __builtin_bit_cast(unsigned int, v.x) & 0x7FFFFFFFu;
        unsigned int u1 = __builtin_bit_cast(unsigned int, v.y) & 0x7FFFFFFFu;
        unsigned int u2 = __builtin_bit_cast(unsigned int, v.z) & 0x7FFFFFFFu;
        unsigned int u3 = __builtin_bit_cast(unsigned int, v.w) & 0x7FFFFFFFu;
        if ((u0 >> 16) == target) atomicAdd(&gh[u0 & 0xFFFFu], 1u);
        if ((u1 >> 16) == target) atomicAdd(&gh[u1 & 0xFFFFu], 1u);
        if ((u2 >> 16) == target) atomicAdd(&gh[u2 & 0xFFFFu], 1u);
        if ((u3 >> 16) == target) atomicAdd(&gh[u3 & 0xFFFFu], 1u);
    }
}

// phase 0: per-tensor hi-bin + rank -> sel[2t],sel[2t+1]. phase 1: final value -> out_kth.
__global__ __launch_bounds__(256) void scan5(
    const unsigned int* __restrict__ hist, int bins, unsigned int* sel,
    float* out_kth, long k0, int phase) {
    int ten = blockIdx.x;
    const unsigned int* h = hist + (long)ten * bins;
    __shared__ unsigned int part[256];
    int t = threadIdx.x;
    int chunk = bins / 256;
    unsigned int s = 0;
    for (int b = 0; b < chunk; ++b) s += h[t * chunk + b];
    part[t] = s;
    __syncthreads();
    if (t == 0) {
        long kk = (phase == 0) ? k0 : (long)sel[2 * ten + 1];
        long c = 0;
        int ch = 0;
        for (; ch < 256; ++ch) {
            if (c + (long)part[ch] >= kk) break;
            c += part[ch];
        }
        int bin = ch * chunk;
        for (;; ++bin) {
            unsigned int hv = h[bin];
            if (c + (long)hv >= kk) break;
            c += hv;
        }
        if (phase == 0) { sel[2 * ten] = (unsigned int)bin; sel[2 * ten + 1] = (unsigned int)(kk - c); }
        else {
            int slot = (ten == 4) ? 5 : ten;
            unsigned int bits = (sel[2 * ten] << 16) | (unsigned int)bin;
            out_kth[slot] = __builtin_bit_cast(float, bits);
        }
    }
}

// P (softmax probs) in [0,1] -> bf16 bits <= 0x3F80 -> 16384 bins (64 KB LDS).
__global__ __launch_bounds__(256, 2) void hist_bf16_p(
    const unsigned short* __restrict__ p, long nv, unsigned int* __restrict__ hist) {
    __shared__ unsigned int lh[16384];
    int t = threadIdx.x;
    for (int b = t; b < 16384; b += 256) lh[b] = 0u;
    __syncthreads();
    long i = (long)blockIdx.x * 256 + t;
    long stride = (long)gridDim.x * 256;
    unsigned int zc = 0;
    for (; i < nv; i += stride) {
        long r = i >> 7;
        int c = (int)(i & 127) * 8;
        ushort8v v = *(const ushort8v*)(p + (r << 11) + c);
        for (int j = 0; j < 8; ++j) {
            unsigned int b = v[j];
            if (b == 0) zc++;
            else atomicAdd(&lh[b < 16384u ? b : 16383u], 1u);
        }
    }
    if (zc) atomicAdd(&lh[0], zc);
    __syncthreads();
    for (int b = t; b < 16384; b += 256) {
        unsigned int c = lh[b];
        if (c) atomicAdd(&hist[b], c);
    }
}

__global__ __launch_bounds__(256) void scan_bf16(
    const unsigned int* __restrict__ hist, float* outp, long k) {
    __shared__ unsigned int part[256];
    int t = threadIdx.x;
    unsigned int s = 0;
    for (int b = 0; b < 64; ++b) s += hist[t * 64 + b];
    part[t] = s;
    __syncthreads();
    if (t == 0) {
        long c = 0;
        int ch = 0;
        for (; ch < 256; ++ch) {
            if (c + (long)part[ch] >= k) break;
            c += part[ch];
        }
        int bin = ch * 64;
        for (;; ++bin) {
            unsigned int h = hist[bin];
            if (c + (long)h >= k) break;
            c += h;
        }
        *outp = __builtin_bit_cast(float, (unsigned int)bin << 16);
    }
}

// ==================================================================
extern "C" void kernel_launch(void* const* d_in, const int* in_sizes, int n_in,
                              void* d_out, int out_size, void* d_ws, size_t ws_size,
                              hipStream_t stream) {
    (void)in_sizes; (void)n_in; (void)out_size; (void)ws_size;
    const float* x = (const float*)d_in[0];
    const int*   wcodes[4] = {(const int*)d_in[1], (const int*)d_in[6],
                              (const int*)d_in[11], (const int*)d_in[16]};
    const float* wabs[4]   = {(const float*)d_in[2], (const float*)d_in[7],
                              (const float*)d_in[12], (const float*)d_in[17]};
    const float* bias[4]   = {(const float*)d_in[3], (const float*)d_in[8],
                              (const float*)d_in[13], (const float*)d_in[18]};
    const float* lA[4]     = {(const float*)d_in[4], (const float*)d_in[9],
                              (const float*)d_in[14], (const float*)d_in[19]};
    const float* lB[4]     = {(const float*)d_in[5], (const float*)d_in[10],
                              (const float*)d_in[15], (const float*)d_in[20]};

    char* wp = (char*)d_ws;
    auto alloc = [&](size_t bytes) {
        char* p = wp; wp += (bytes + 255) & ~(size_t)255; return p;
    };
    const size_t SH  = (size_t)S_LEN * H_DIM;       // 4,194,304
    const long   nW  = (long)H_DIM * H_DIM;
    unsigned short* xb = (unsigned short*)alloc(SH * 2);
    unsigned short* qb = (unsigned short*)alloc(SH * 2);   // qb,kb contiguous
    unsigned short* kb = (unsigned short*)alloc(SH * 2);
    unsigned short* vT = (unsigned short*)alloc(SH * 2);
    unsigned short* ob = (unsigned short*)alloc(SH * 2);
    unsigned short* Wd = (unsigned short*)alloc((size_t)nW * 2);   // O-proj weight
    float* qf = (float*)alloc(SH * 4);                     // qf,kf,vf,of contiguous
    float* kf = (float*)alloc(SH * 4);
    float* vf = (float*)alloc(SH * 4);
    float* of = (float*)alloc(SH * 4);
    float* opart = (float*)alloc(SH * 4);                  // O-proj split-K partial
    float* laout = (float*)alloc((size_t)S_LEN * RANK * 4);
    unsigned int* histHi = (unsigned int*)alloc(5 * 16384 * 4);
    unsigned int* histLo = (unsigned int*)alloc(5 * 65536 * 4);
    unsigned int* histP  = (unsigned int*)alloc(16384 * 4);
    unsigned int* sel    = (unsigned int*)alloc(256);
    // scores (128 MB) doubles as QKV dequant buffer (96 MB) before attention
    float* scores = (float*)alloc((size_t)NHEAD * S_LEN * S_LEN * 4);
    unsigned short* Wqkv = (unsigned short*)scores;

    float* out_final = (float*)d_out;
    float* out_kth   = out_final + SH;

    // x -> bf16
    f32_to_bf16_kernel<<<2048, 256, 0, stream>>>(x, xb, (long)SH);

    // Q/K/V: dequant all 3 weights (one launch), then ONE z=3 batched GEMM (768 blocks)
    dequant3_kernel<<<dim3(8192, 3), 256, 0, stream>>>(
        wcodes[0], wcodes[1], wcodes[2], wabs[0], wabs[1], wabs[2], Wqkv, nW);
    gemm_nt<<<dim3(32, 8, 3), 256, 0, stream>>>(
        xb, Wqkv, qf, nullptr, H_DIM, H_DIM, H_DIM, H_DIM,
        0, nW, (long)SH, 1.0f, 0);
    float* outs[3] = {qf, kf, vf};
    for (int p = 0; p < 3; ++p) {
        lora_a_kernel<<<S_LEN, 256, 0, stream>>>(x, lA[p], laout);
        bias_lora_kernel<<<4096, 256, 0, stream>>>(outs[p], nullptr, bias[p], laout, lB[p]);
    }

    // attention inputs: q,k -> bf16 (one launch, contiguous), v -> vT
    f32_to_bf16_kernel<<<4096, 256, 0, stream>>>(qf, qb, (long)(2 * SH));
    transpose_bf16_kernel<<<dim3(H_DIM / 32, S_LEN / 32), dim3(32, 32), 0, stream>>>(vf, vT);

    // scores = q.kT / sqrt(128): only 36 lower-triangular tiles per head (mode 1)
    gemm_nt<<<dim3(36, 1, NHEAD), 256, 0, stream>>>(
        qb, kb, scores, nullptr, HEAD_D, H_DIM, H_DIM, S_LEN,
        128, 128, (long)S_LEN * S_LEN, 0.08838834764831845f, 1);
    softmax_causal<<<NHEAD * S_LEN, 256, 0, stream>>>(scores);
    // o = P.v  (P bf16, row stride 2048); mode 2 limits K to bm+128
    gemm_nt<<<dim3(1, 8, NHEAD), 256, 0, stream>>>(
        (const unsigned short*)scores, vT, of, nullptr, S_LEN,
        2 * S_LEN, S_LEN, H_DIM,
        (long)S_LEN * 2 * S_LEN, (long)HEAD_D * S_LEN, 128, 1.0f, 2);

    // O projection -> d_out: split-K2 in one dispatch (z=2), partial summed in bias_lora
    f32_to_bf16_kernel<<<2048, 256, 0, stream>>>(of, ob, (long)SH);
    dequant_nf4_kernel<<<8192, 256, 0, stream>>>(wcodes[3], wabs[3], Wd, nW);
    gemm_nt<<<dim3(32, 8, 2), 256, 0, stream>>>(
        ob, Wd, out_final, opart, H_DIM, H_DIM, H_DIM, H_DIM,
        0, 0, 0, 1.0f, 3);
    lora_a_kernel<<<S_LEN, 256, 0, stream>>>(of, lA[3], laout);
    bias_lora_kernel<<<4096, 256, 0, stream>>>(out_final, opart, bias[3], laout, lB[3]);

    // k-th smallest: merged 5-tensor radix select (x,qf,kf,vf -> slots 0-3, of -> 5)
    hipMemsetAsync(histHi, 0, 5 * 16384 * 4, stream);
    hist5_hi<<<dim3(192, 5), 256, 0, stream>>>(x, qf, kf, vf, of, (long)SH / 4, histHi);
    scan5<<<5, 256, 0, stream>>>(histHi, 16384, sel, out_kth, (long)SH / 2, 0);
    hipMemsetAsync(histLo, 0, 5 * 65536 * 4, stream);
    hist5_lo<<<dim3(192, 5), 256, 0, stream>>>(x, qf, kf, vf, of, (long)SH / 4, sel, histLo);
    scan5<<<5, 256, 0, stream>>>(histLo, 65536, sel, out_kth, 0, 1);
    // P (attention probs) select -> slot 4
    hipMemsetAsync(histP, 0, 16384 * 4, stream);
    hist_bf16_p<<<1024, 256, 0, stream>>>((const unsigned short*)scores,
                                          (long)NHEAD * S_LEN * S_LEN / 8, histP);
    scan_bf16<<<1, 256, 0, stream>>>(histP, out_kth + 4,
                                     (long)NHEAD * S_LEN * S_LEN / 2);
}